// Round 6
// baseline (449.497 us; speedup 1.0000x reference)
//
#include <hip/hip_runtime.h>
#include <cstddef>
#include <cstdint>

// ---------------------------------------------------------------------------
// AttentionSubsample (LeViT-style), B=64, C=256, H=8, KD=16, D=32,
// N=784 (28x28), N_=196 (14x14), stride 2.
//
// Round 5: round-3 pipeline with the gemm_kv channel-routing fix:
//   kv channel o maps to (h = o/48, c = o%48); K = c<16, V = c>=16.
//  1. wprep x3 : W -> bf16 hi/lo [o][c]
//  2. xprep    : x -> bf16 hi/lo 64x64 tiles, XOR-swizzled, LDS-linear order
//  3. bias     : biasB[h][m][208] bf16
//  4. gemm_kv  : (async-staged B) -> Kt hi/lo [b][h][m][16], Vbf [b][h][32][m]
//  5. gemm_q   : (gather-staged B) -> Qt hi/lo [b][h][n][16]
//  6. attn     : all operands direct-global fragments; out -> actT swz tiles
//  7. gemm_proj: (async-staged B from actT) -> d_out fp32
// ---------------------------------------------------------------------------

#define SCALE_ATTN 0.25f
#define BN_EPS 1e-5f

typedef short s8v __attribute__((ext_vector_type(8)));
typedef short s4v __attribute__((ext_vector_type(4)));
typedef float f4v __attribute__((ext_vector_type(4)));

__device__ __forceinline__ float hswish(float y) {
    float t = fminf(fmaxf(y + 3.0f, 0.0f), 6.0f);
    return y * t * (1.0f / 6.0f);
}
__device__ __forceinline__ unsigned short bf16_rn(float f) {
    unsigned u = __float_as_uint(f);
    unsigned r = (u + 0x7FFFu + ((u >> 16) & 1u)) >> 16;
    return (unsigned short)r;
}
__device__ __forceinline__ float bf16_to_f(unsigned short h) {
    return __uint_as_float(((unsigned)h) << 16);
}
__device__ __forceinline__ void gload_lds16(const void* gsrc, void* ldsdst) {
    __builtin_amdgcn_global_load_lds(
        (const __attribute__((address_space(1))) unsigned int*)gsrc,
        (__attribute__((address_space(3))) unsigned int*)ldsdst, 16, 0, 0);
}

// ---------------- W pre-convert: fp32 [o][c] -> bf16 hi/lo ----------------
__global__ __launch_bounds__(256)
void wprep(const float* __restrict__ W, short* __restrict__ hi,
           short* __restrict__ lo, int n4)
{
    int i = blockIdx.x * 256 + threadIdx.x;
    int stride = gridDim.x * 256;
    for (; i < n4; i += stride) {
        float4 v = reinterpret_cast<const float4*>(W)[i];
        s4v h, l;
        unsigned short hh;
        hh = bf16_rn(v.x); h[0] = (short)hh; l[0] = (short)bf16_rn(v.x - bf16_to_f(hh));
        hh = bf16_rn(v.y); h[1] = (short)hh; l[1] = (short)bf16_rn(v.y - bf16_to_f(hh));
        hh = bf16_rn(v.z); h[2] = (short)hh; l[2] = (short)bf16_rn(v.z - bf16_to_f(hh));
        hh = bf16_rn(v.w); h[3] = (short)hh; l[3] = (short)bf16_rn(v.w - bf16_to_f(hh));
        reinterpret_cast<s4v*>(hi)[i] = h;
        reinterpret_cast<s4v*>(lo)[i] = l;
    }
}

// ---------------- x pre-pass: transpose + split + swizzle into tiles -------
// tile (b, nt, ct): 16 KB = [hi 64r x 64c swz 8KB][lo 8KB]; r = n&63, c chunk-local
__global__ __launch_bounds__(256)
void xprep(const float* __restrict__ x, short* __restrict__ xT)
{
    __shared__ float T[64][65];
    int nt = blockIdx.x, b = blockIdx.y;
    int n0 = nt * 64;
    const float* xb = x + (size_t)b * 256 * 784;
    int t = threadIdx.x;
    int cr = t >> 2, s = t & 3;

    for (int ct = 0; ct < 4; ++ct) {
        __syncthreads();
#pragma unroll
        for (int qq = 0; qq < 4; ++qq) {
            int n = n0 + s * 16 + qq * 4;
            float4 v = make_float4(0.f, 0.f, 0.f, 0.f);
            if (n + 3 < 784)
                v = *reinterpret_cast<const float4*>(&xb[(size_t)(ct * 64 + cr) * 784 + n]);
            *reinterpret_cast<float4*>(&T[cr][s * 16 + qq * 4]) = v;
        }
        __syncthreads();
        int r = cr;
        if (n0 + r < 784) {
            size_t tb = ((((size_t)b * 13 + nt) * 4 + ct) << 13);  // shorts
            short* hiB = xT + tb;
            short* loB = xT + tb + 4096;
            s8v h0, h1, l0, l1;
#pragma unroll
            for (int j = 0; j < 8; ++j) {
                float f = T[s * 16 + j][r];
                unsigned short hh = bf16_rn(f);
                h0[j] = (short)hh; l0[j] = (short)bf16_rn(f - bf16_to_f(hh));
            }
#pragma unroll
            for (int j = 0; j < 8; ++j) {
                float f = T[s * 16 + 8 + j][r];
                unsigned short hh = bf16_rn(f);
                h1[j] = (short)hh; l1[j] = (short)bf16_rn(f - bf16_to_f(hh));
            }
            int sw = (r & 7) << 3;
            int base = r * 64;
            *reinterpret_cast<s8v*>(&hiB[base + ((s * 16) ^ sw)]) = h0;
            *reinterpret_cast<s8v*>(&hiB[base + ((s * 16 + 8) ^ sw)]) = h1;
            *reinterpret_cast<s8v*>(&loB[base + ((s * 16) ^ sw)]) = l0;
            *reinterpret_cast<s8v*>(&loB[base + ((s * 16 + 8) ^ sw)]) = l1;
        }
    }
}

// ---------------- bias precompute (bf16, transposed, padded to 208) -------
__global__ __launch_bounds__(256)
void bias_kernel(const float* __restrict__ ab, const int* __restrict__ idxs,
                 unsigned short* __restrict__ biasB, int n_off)
{
    __shared__ int I[32][33];
    int mx = blockIdx.x * 32, ny = blockIdx.y * 32;
    int tx = threadIdx.x & 31, ty = threadIdx.x >> 5;
#pragma unroll
    for (int i = 0; i < 4; ++i) {
        int nl = ty + i * 8;
        int n = ny + nl, m = mx + tx;
        I[tx][nl] = (n < 196 && m < 784) ? idxs[n * 784 + m] : 0;
    }
    __syncthreads();
#pragma unroll
    for (int i = 0; i < 4; ++i) {
        int ml = ty + i * 8;
        int m = mx + ml, n = ny + tx;
        if (m < 784 && n < 208) {
            if (n < 196) {
                int id = I[ml][tx];
#pragma unroll
                for (int h = 0; h < 8; ++h)
                    biasB[((size_t)h * 784 + m) * 208 + n] = bf16_rn(ab[h * n_off + id]);
            } else {
#pragma unroll
                for (int h = 0; h < 8; ++h)
                    biasB[((size_t)h * 784 + m) * 208 + n] = 0;
            }
        }
    }
}

// ---------------- kv GEMM: 128o x 64n, async-staged swizzled B -------------
// channel o -> h = o/48, c = o%48; c<16 -> Kt hi/lo [b][h][m][16];
//                                  c>=16 -> Vbf [b][h][32][m] (d = c-16)
__global__ __launch_bounds__(256)
void gemm_kv(const short* __restrict__ xT,
             const short* __restrict__ Whi, const short* __restrict__ Wlo,
             const float* __restrict__ G, const float* __restrict__ Bb,
             const float* __restrict__ Mm, const float* __restrict__ Vv,
             short* __restrict__ Kthi, short* __restrict__ Ktlo,
             short* __restrict__ Vbf)
{
    __shared__ short Bt[2][64][64];
    __shared__ float scs[128], shs[128];

    int nt = blockIdx.x, oy = blockIdx.y, b = blockIdx.z;
    int oBase = oy * 128;
    int tid = threadIdx.x, w = tid >> 6, l = tid & 63;
    int fr = l & 15, g = l >> 4;

    if (tid < 128) {
        int o = oBase + tid;
        float sc = G[o] * rsqrtf(Vv[o] + BN_EPS);
        scs[tid] = sc; shs[tid] = Bb[o] - Mm[o] * sc;
    }

    f4v acc[2][4];
#pragma unroll
    for (int i = 0; i < 2; ++i)
#pragma unroll
        for (int j = 0; j < 4; ++j) acc[i][j] = (f4v)0.0f;

    const char* tilesrc = (const char*)(xT) + ((((size_t)b * 13 + nt) * 4) << 14);
    char* ldsbase = (char*)&Bt[0][0][0];

    for (int ct = 0; ct < 4; ++ct) {
        __syncthreads();
        {
            const char* src = tilesrc + ((size_t)ct << 14) + w * 4096 + l * 16;
            char* dst = ldsbase + w * 4096;
#pragma unroll
            for (int j = 0; j < 4; ++j)
                gload_lds16(src + j * 1024, dst + j * 1024);
        }
        __syncthreads();
#pragma unroll
        for (int ks = 0; ks < 2; ++ks) {
            s8v ah[2], al[2];
#pragma unroll
            for (int mf = 0; mf < 2; ++mf) {
                int o = oBase + w * 32 + mf * 16 + fr;
                size_t wi = (size_t)o * 256 + ct * 64 + ks * 32 + g * 8;
                ah[mf] = *reinterpret_cast<const s8v*>(&Whi[wi]);
                al[mf] = *reinterpret_cast<const s8v*>(&Wlo[wi]);
            }
#pragma unroll
            for (int nf = 0; nf < 4; ++nf) {
                int r = nf * 16 + fr;
                int ci = (ks * 32 + g * 8) ^ ((r & 7) << 3);
                s8v bh = *reinterpret_cast<const s8v*>(&Bt[0][r][ci]);
                s8v bl = *reinterpret_cast<const s8v*>(&Bt[1][r][ci]);
#pragma unroll
                for (int mf = 0; mf < 2; ++mf) {
                    acc[mf][nf] = __builtin_amdgcn_mfma_f32_16x16x32_bf16(ah[mf], bh, acc[mf][nf], 0, 0, 0);
                    acc[mf][nf] = __builtin_amdgcn_mfma_f32_16x16x32_bf16(ah[mf], bl, acc[mf][nf], 0, 0, 0);
                    acc[mf][nf] = __builtin_amdgcn_mfma_f32_16x16x32_bf16(al[mf], bh, acc[mf][nf], 0, 0, 0);
                }
            }
        }
    }

    int nBase = nt * 64;
#pragma unroll
    for (int mf = 0; mf < 2; ++mf) {
        int ol = w * 32 + mf * 16 + g * 4;    // 4-aligned; run of 4 stays in one (h, K/V) region
        int o = oBase + ol;
        int h = o / 48;
        int c = o - h * 48;
        if (c < 16) {
            // ---- K channels c..c+3 of head h ----
#pragma unroll
            for (int nf = 0; nf < 4; ++nf) {
                int n = nBase + nf * 16 + fr;
                if (n < 784) {
                    s4v hv, lv;
#pragma unroll
                    for (int e = 0; e < 4; ++e) {
                        float z = hswish(acc[mf][nf][e] * scs[ol + e] + shs[ol + e]);
                        unsigned short hh = bf16_rn(z);
                        hv[e] = (short)hh; lv[e] = (short)bf16_rn(z - bf16_to_f(hh));
                    }
                    size_t ki = (((size_t)b * 8 + h) * 784 + n) * 16 + c;
                    *reinterpret_cast<s4v*>(&Kthi[ki]) = hv;
                    *reinterpret_cast<s4v*>(&Ktlo[ki]) = lv;
                }
            }
        } else {
            // ---- V channels d..d+3 of head h ----
            int d = c - 16;
#pragma unroll
            for (int nf = 0; nf < 4; ++nf) {
                int n = nBase + nf * 16 + fr;
                if (n < 784) {
#pragma unroll
                    for (int e = 0; e < 4; ++e) {
                        float z = hswish(acc[mf][nf][e] * scs[ol + e] + shs[ol + e]);
                        Vbf[(((size_t)b * 8 + h) * 32 + d + e) * 784 + n] = (short)bf16_rn(z);
                    }
                }
            }
        }
    }
}

// ---------------- q GEMM: 128o x 64n, gather-staged B (strided x) ----------
__global__ __launch_bounds__(256)
void gemm_q(const float* __restrict__ x,
            const short* __restrict__ Whi, const short* __restrict__ Wlo,
            const float* __restrict__ G, const float* __restrict__ Bb,
            const float* __restrict__ Mm, const float* __restrict__ Vv,
            short* __restrict__ Qthi, short* __restrict__ Qtlo)
{
    __shared__ short Bt[2][64][64];
    __shared__ float scs[128], shs[128];

    int nt = blockIdx.x, b = blockIdx.z;
    const float* xb = x + (size_t)b * 256 * 784;
    int tid = threadIdx.x, w = tid >> 6, l = tid & 63;
    int fr = l & 15, g = l >> 4;
    int sr = tid >> 4, sc4 = (tid & 15) * 4;

    if (tid < 128) {
        int o = tid;
        float sc = G[o] * rsqrtf(Vv[o] + BN_EPS);
        scs[tid] = sc; shs[tid] = Bb[o] - Mm[o] * sc;
    }

    f4v acc[2][4];
#pragma unroll
    for (int i = 0; i < 2; ++i)
#pragma unroll
        for (int j = 0; j < 4; ++j) acc[i][j] = (f4v)0.0f;

    for (int ct = 0; ct < 4; ++ct) {
        __syncthreads();
#pragma unroll
        for (int jc = 0; jc < 4; ++jc) {
            int c = sr + jc * 16;
#pragma unroll
            for (int e = 0; e < 4; ++e) {
                int nn = nt * 64 + sc4 + e;
                float v = 0.0f;
                if (nn < 196) {
                    int rr = nn / 14, cc = nn - rr * 14;
                    v = xb[(size_t)(ct * 64 + c) * 784 + rr * 56 + cc * 2];
                }
                int r = sc4 + e;
                int ci = c ^ ((r & 7) << 3);
                unsigned short hh = bf16_rn(v);
                Bt[0][r][ci] = (short)hh;
                Bt[1][r][ci] = (short)bf16_rn(v - bf16_to_f(hh));
            }
        }
        __syncthreads();
#pragma unroll
        for (int ks = 0; ks < 2; ++ks) {
            s8v ah[2], al[2];
#pragma unroll
            for (int mf = 0; mf < 2; ++mf) {
                int o = w * 32 + mf * 16 + fr;
                size_t wi = (size_t)o * 256 + ct * 64 + ks * 32 + g * 8;
                ah[mf] = *reinterpret_cast<const s8v*>(&Whi[wi]);
                al[mf] = *reinterpret_cast<const s8v*>(&Wlo[wi]);
            }
#pragma unroll
            for (int nf = 0; nf < 4; ++nf) {
                int r = nf * 16 + fr;
                int ci = (ks * 32 + g * 8) ^ ((r & 7) << 3);
                s8v bh = *reinterpret_cast<const s8v*>(&Bt[0][r][ci]);
                s8v bl = *reinterpret_cast<const s8v*>(&Bt[1][r][ci]);
#pragma unroll
                for (int mf = 0; mf < 2; ++mf) {
                    acc[mf][nf] = __builtin_amdgcn_mfma_f32_16x16x32_bf16(ah[mf], bh, acc[mf][nf], 0, 0, 0);
                    acc[mf][nf] = __builtin_amdgcn_mfma_f32_16x16x32_bf16(ah[mf], bl, acc[mf][nf], 0, 0, 0);
                    acc[mf][nf] = __builtin_amdgcn_mfma_f32_16x16x32_bf16(al[mf], bh, acc[mf][nf], 0, 0, 0);
                }
            }
        }
    }

#pragma unroll
    for (int mf = 0; mf < 2; ++mf) {
        int ol = w * 32 + mf * 16 + g * 4;
        int h = ol >> 4, d0 = ol & 15;
#pragma unroll
        for (int nf = 0; nf < 4; ++nf) {
            int n = nt * 64 + nf * 16 + fr;
            if (n < 196) {
                s4v hv, lv;
#pragma unroll
                for (int e = 0; e < 4; ++e) {
                    float z = hswish(acc[mf][nf][e] * scs[ol + e] + shs[ol + e]);
                    unsigned short hh = bf16_rn(z);
                    hv[e] = (short)hh; lv[e] = (short)bf16_rn(z - bf16_to_f(hh));
                }
                size_t qi = (((size_t)b * 8 + h) * 196 + n) * 16 + d0;
                *reinterpret_cast<s4v*>(&Qthi[qi]) = hv;
                *reinterpret_cast<s4v*>(&Qtlo[qi]) = lv;
            }
        }
    }
}

// ---------------- attention: direct-global fragments, no barriers ----------
__global__ __launch_bounds__(512)
void attn_mfma(const short* __restrict__ Kthi, const short* __restrict__ Ktlo,
               const short* __restrict__ Vbf,
               const short* __restrict__ Qthi, const short* __restrict__ Qtlo,
               const unsigned short* __restrict__ biasB, short* __restrict__ actT)
{
    __shared__ short Pl[8][16][72];

    int bh = blockIdx.x;
    int b = bh >> 3, h = bh & 7;
    const short* Kh = Kthi + (size_t)bh * 784 * 16;
    const short* Kl = Ktlo + (size_t)bh * 784 * 16;
    const short* Vb = Vbf + (size_t)bh * 32 * 784;
    const short* Qh = Qthi + (size_t)bh * 196 * 16;
    const short* Ql = Qtlo + (size_t)bh * 196 * 16;
    const unsigned short* bB = biasB + (size_t)h * 784 * 208;

    int tid = threadIdx.x, w = tid >> 6, l = tid & 63;
    int g = l >> 4, fr = l & 15;

    int ntc = (w < 5) ? 2 : 1;
    int ntile[2] = { w, 8 + w };

    s8v qh[2], ql[2];
#pragma unroll
    for (int i = 0; i < 2; ++i) { qh[i] = (s8v)0; ql[i] = (s8v)0; }
#pragma unroll
    for (int i = 0; i < 2; ++i) {
        if (i < ntc && g < 2) {
            int n = ntile[i] * 16 + fr;
            if (n < 196) {
                qh[i] = *reinterpret_cast<const s8v*>(&Qh[(size_t)n * 16 + g * 8]);
                ql[i] = *reinterpret_cast<const s8v*>(&Ql[(size_t)n * 16 + g * 8]);
            }
        }
    }

    f4v Oa[2][2];
    float M[2], L[2];
#pragma unroll
    for (int i = 0; i < 2; ++i) {
        Oa[i][0] = (f4v)0.0f; Oa[i][1] = (f4v)0.0f;
        M[i] = -1e30f; L[i] = 0.0f;
    }

#pragma unroll 1
    for (int ch = 0; ch < 13; ++ch) {
        int m0 = ch * 64;
        int subLim = (ch == 12) ? 1 : 4;
        int mlim = (ch == 12) ? 16 : 64;
#pragma unroll 1
        for (int i = 0; i < 2; ++i) {
            if (i >= ntc) continue;
            int n = ntile[i] * 16 + fr;

            float s[4][4];
#pragma unroll
            for (int sub = 0; sub < 4; ++sub) {
                if (sub < subLim) {
                    int mg = m0 + sub * 16 + fr;
                    s8v ah = (s8v)0, al = (s8v)0;
                    if (g < 2) {
                        ah = *reinterpret_cast<const s8v*>(&Kh[(size_t)mg * 16 + g * 8]);
                        al = *reinterpret_cast<const s8v*>(&Kl[(size_t)mg * 16 + g * 8]);
                    }
                    f4v a = (f4v)0.0f;
                    a = __builtin_amdgcn_mfma_f32_16x16x32_bf16(ah, qh[i], a, 0, 0, 0);
                    a = __builtin_amdgcn_mfma_f32_16x16x32_bf16(ah, ql[i], a, 0, 0, 0);
                    a = __builtin_amdgcn_mfma_f32_16x16x32_bf16(al, qh[i], a, 0, 0, 0);
#pragma unroll
                    for (int e = 0; e < 4; ++e) {
                        int mm = m0 + sub * 16 + g * 4 + e;
                        float bia = bf16_to_f(bB[(size_t)mm * 208 + n]);
                        s[sub][e] = a[e] * SCALE_ATTN + bia;
                    }
                } else {
#pragma unroll
                    for (int e = 0; e < 4; ++e) s[sub][e] = -1e30f;
                }
            }

            float mx = s[0][0];
#pragma unroll
            for (int sub = 0; sub < 4; ++sub)
#pragma unroll
                for (int e = 0; e < 4; ++e) mx = fmaxf(mx, s[sub][e]);
            mx = fmaxf(mx, __shfl_xor(mx, 16));
            mx = fmaxf(mx, __shfl_xor(mx, 32));
            if (__any(mx > M[i] + 8.0f)) {
                float Mn = fmaxf(M[i], mx);
                float corr = __expf(M[i] - Mn);
                L[i] *= corr;
#pragma unroll
                for (int e = 0; e < 4; ++e) { Oa[i][0][e] *= corr; Oa[i][1][e] *= corr; }
                M[i] = Mn;
            }

            float Ls = 0.0f;
#pragma unroll
            for (int sub = 0; sub < 4; ++sub) {
                float p[4];
#pragma unroll
                for (int e = 0; e < 4; ++e) {
                    int mml = sub * 16 + g * 4 + e;
                    float pv = __expf(s[sub][e] - M[i]);
                    p[e] = (mml < mlim) ? pv : 0.0f;
                    Ls += p[e];
                }
                unsigned w0 = (unsigned)bf16_rn(p[0]) | ((unsigned)bf16_rn(p[1]) << 16);
                unsigned w1 = (unsigned)bf16_rn(p[2]) | ((unsigned)bf16_rn(p[3]) << 16);
                int mb = sub * 16 + g * 4;
                *reinterpret_cast<unsigned*>(&Pl[w][fr][mb]) = w0;
                *reinterpret_cast<unsigned*>(&Pl[w][fr][mb + 2]) = w1;
            }
            Ls += __shfl_xor(Ls, 16);
            Ls += __shfl_xor(Ls, 32);
            L[i] += Ls;

#pragma unroll
            for (int kc = 0; kc < 2; ++kc) {
                s8v pf = *reinterpret_cast<const s8v*>(&Pl[w][fr][kc * 32 + g * 8]);
                int mf0 = m0 + kc * 32 + g * 8;
                s8v v0 = (s8v)0, v1 = (s8v)0;
                if (mf0 + 8 <= 784) {
                    v0 = *reinterpret_cast<const s8v*>(&Vb[(size_t)fr * 784 + mf0]);
                    v1 = *reinterpret_cast<const s8v*>(&Vb[(size_t)(16 + fr) * 784 + mf0]);
                }
                Oa[i][0] = __builtin_amdgcn_mfma_f32_16x16x32_bf16(v0, pf, Oa[i][0], 0, 0, 0);
                Oa[i][1] = __builtin_amdgcn_mfma_f32_16x16x32_bf16(v1, pf, Oa[i][1], 0, 0, 0);
            }
        }
    }

    // epilogue -> actT swizzled hi/lo tiles
#pragma unroll
    for (int i = 0; i < 2; ++i) {
        if (i >= ntc) continue;
        int n = ntile[i] * 16 + fr;
        if (n < 196) {
            float inv = 1.0f / L[i];
            int r = n & 63, ntl = n >> 6;
            int sw = (r & 7) << 3;
#pragma unroll
            for (int dt = 0; dt < 2; ++dt) {
                int c0 = h * 32 + dt * 16 + g * 4;
                s4v hv, lv;
#pragma unroll
                for (int e = 0; e < 4; ++e) {
                    float z = hswish(Oa[i][dt][e] * inv);
                    unsigned short hh = bf16_rn(z);
                    hv[e] = (short)hh; lv[e] = (short)bf16_rn(z - bf16_to_f(hh));
                }
                int ct = c0 >> 6, c2 = c0 & 63;
                size_t tb = ((((size_t)b * 4 + ntl) * 4 + ct) << 13);  // shorts
                int idx = r * 64 + (c2 ^ sw);
                *reinterpret_cast<s4v*>(&actT[tb + idx]) = hv;
                *reinterpret_cast<s4v*>(&actT[tb + 4096 + idx]) = lv;
            }
        }
    }
}

// ---------------- proj GEMM: 128o x 64n from actT tiles -> fp32 out --------
__global__ __launch_bounds__(256)
void gemm_proj(const short* __restrict__ actT,
               const short* __restrict__ Whi, const short* __restrict__ Wlo,
               const float* __restrict__ G, const float* __restrict__ Bb,
               const float* __restrict__ Mm, const float* __restrict__ Vv,
               float* __restrict__ out)
{
    __shared__ short Bt[2][64][64];
    __shared__ float scs[128], shs[128];

    int nt = blockIdx.x, oy = blockIdx.y, b = blockIdx.z;
    int oBase = oy * 128;
    int tid = threadIdx.x, w = tid >> 6, l = tid & 63;
    int fr = l & 15, g = l >> 4;

    if (tid < 128) {
        int o = oBase + tid;
        float sc = G[o] * rsqrtf(Vv[o] + BN_EPS);
        scs[tid] = sc; shs[tid] = Bb[o] - Mm[o] * sc;
    }

    f4v acc[2][4];
#pragma unroll
    for (int i = 0; i < 2; ++i)
#pragma unroll
        for (int j = 0; j < 4; ++j) acc[i][j] = (f4v)0.0f;

    const char* tilesrc = (const char*)(actT) + ((((size_t)b * 4 + nt) * 4) << 14);
    char* ldsbase = (char*)&Bt[0][0][0];

    for (int ct = 0; ct < 4; ++ct) {
        __syncthreads();
        {
            const char* src = tilesrc + ((size_t)ct << 14) + w * 4096 + l * 16;
            char* dst = ldsbase + w * 4096;
#pragma unroll
            for (int j = 0; j < 4; ++j)
                gload_lds16(src + j * 1024, dst + j * 1024);
        }
        __syncthreads();
#pragma unroll
        for (int ks = 0; ks < 2; ++ks) {
            s8v ah[2], al[2];
#pragma unroll
            for (int mf = 0; mf < 2; ++mf) {
                int o = oBase + w * 32 + mf * 16 + fr;
                size_t wi = (size_t)o * 256 + ct * 64 + ks * 32 + g * 8;
                ah[mf] = *reinterpret_cast<const s8v*>(&Whi[wi]);
                al[mf] = *reinterpret_cast<const s8v*>(&Wlo[wi]);
            }
#pragma unroll
            for (int nf = 0; nf < 4; ++nf) {
                int r = nf * 16 + fr;
                int ci = (ks * 32 + g * 8) ^ ((r & 7) << 3);
                s8v bh = *reinterpret_cast<const s8v*>(&Bt[0][r][ci]);
                s8v bl = *reinterpret_cast<const s8v*>(&Bt[1][r][ci]);
#pragma unroll
                for (int mf = 0; mf < 2; ++mf) {
                    acc[mf][nf] = __builtin_amdgcn_mfma_f32_16x16x32_bf16(ah[mf], bh, acc[mf][nf], 0, 0, 0);
                    acc[mf][nf] = __builtin_amdgcn_mfma_f32_16x16x32_bf16(ah[mf], bl, acc[mf][nf], 0, 0, 0);
                    acc[mf][nf] = __builtin_amdgcn_mfma_f32_16x16x32_bf16(al[mf], bh, acc[mf][nf], 0, 0, 0);
                }
            }
        }
    }

#pragma unroll
    for (int mf = 0; mf < 2; ++mf) {
        int ol = w * 32 + mf * 16 + g * 4;
#pragma unroll
        for (int nf = 0; nf < 4; ++nf) {
            int n = nt * 64 + nf * 16 + fr;
            if (n < 196) {
#pragma unroll
                for (int e = 0; e < 4; ++e) {
                    float z = hswish(acc[mf][nf][e] * scs[ol + e] + shs[ol + e]);
                    out[((size_t)b * 512 + oBase + ol + e) * 196 + n] = z;
                }
            }
        }
    }
}

// ---------------------------------------------------------------------------
extern "C" void kernel_launch(void* const* d_in, const int* in_sizes, int n_in,
                              void* d_out, int out_size, void* d_ws, size_t ws_size,
                              hipStream_t stream) {
    const float* x      = (const float*)d_in[0];
    const float* kv_w   = (const float*)d_in[1];
    const float* kv_g   = (const float*)d_in[2];
    const float* kv_b   = (const float*)d_in[3];
    const float* kv_m   = (const float*)d_in[4];
    const float* kv_v   = (const float*)d_in[5];
    const float* q_w    = (const float*)d_in[6];
    const float* q_g    = (const float*)d_in[7];
    const float* q_b    = (const float*)d_in[8];
    const float* q_m    = (const float*)d_in[9];
    const float* q_v    = (const float*)d_in[10];
    const float* proj_w = (const float*)d_in[11];
    const float* proj_g = (const float*)d_in[12];
    const float* proj_b = (const float*)d_in[13];
    const float* proj_m = (const float*)d_in[14];
    const float* proj_v = (const float*)d_in[15];
    const float* ab     = (const float*)d_in[16];
    const int*   idxs   = (const int*)d_in[17];
    float* out = (float*)d_out;

    int n_off = in_sizes[16] / 8;

    // ---- workspace layout (bytes, 256-aligned) ----
    char* p = (char*)d_ws;
    size_t off = 0;
    auto alloc = [&](size_t bytes) -> char* {
        char* r = p + off;
        off += (bytes + 255) & ~(size_t)255;
        return r;
    };
    short* Kthi = (short*)alloc((size_t)64 * 8 * 784 * 16 * 2);
    short* Ktlo = (short*)alloc((size_t)64 * 8 * 784 * 16 * 2);
    short* Vbf  = (short*)alloc((size_t)64 * 8 * 32 * 784 * 2);
    short* Qthi = (short*)alloc((size_t)64 * 8 * 196 * 16 * 2);
    short* Qtlo = (short*)alloc((size_t)64 * 8 * 196 * 16 * 2);
    unsigned short* biasB = (unsigned short*)alloc((size_t)8 * 784 * 208 * 2);
    short* Wkvh = (short*)alloc((size_t)384 * 256 * 2);
    short* Wkvl = (short*)alloc((size_t)384 * 256 * 2);
    short* Wqh  = (short*)alloc((size_t)128 * 256 * 2);
    short* Wql  = (short*)alloc((size_t)128 * 256 * 2);
    short* Wpjh = (short*)alloc((size_t)512 * 256 * 2);
    short* Wpjl = (short*)alloc((size_t)512 * 256 * 2);
    short* xT   = (short*)alloc((size_t)64 * 13 * 4 * 16384);
    short* actT = xT;   // alias: xT consumed by gemm_kv before attn writes actT

    // 1. W pre-converts
    wprep<<<dim3(64), 256, 0, stream>>>(kv_w, Wkvh, Wkvl, 384 * 256 / 4);
    wprep<<<dim3(64), 256, 0, stream>>>(q_w, Wqh, Wql, 128 * 256 / 4);
    wprep<<<dim3(64), 256, 0, stream>>>(proj_w, Wpjh, Wpjl, 512 * 256 / 4);
    // 2. x transpose/convert/swizzle tiles
    xprep<<<dim3(13, 64), 256, 0, stream>>>(x, xT);
    // 3. bias gather (bf16)
    bias_kernel<<<dim3(25, 7), 256, 0, stream>>>(ab, idxs, biasB, n_off);
    // 4. kv GEMM -> Kt hi/lo + Vbf (correct h*48+c channel routing)
    gemm_kv<<<dim3(13, 3, 64), 256, 0, stream>>>(xT, Wkvh, Wkvl, kv_g, kv_b, kv_m, kv_v,
                                                 Kthi, Ktlo, Vbf);
    // 5. q GEMM -> Qt hi/lo
    gemm_q<<<dim3(4, 1, 64), 256, 0, stream>>>(x, Wqh, Wql, q_g, q_b, q_m, q_v,
                                               Qthi, Qtlo);
    // 6. attention -> actT tiles
    attn_mfma<<<dim3(512), 512, 0, stream>>>(Kthi, Ktlo, Vbf, Qthi, Qtlo, biasB, actT);
    // 7. proj GEMM -> out
    gemm_proj<<<dim3(4, 4, 64), 256, 0, stream>>>(actT, Wpjh, Wpjl,
                                                  proj_g, proj_b, proj_m, proj_v, out);
}

// Round 8
// 387.731 us; speedup vs baseline: 1.1593x; 1.1593x over previous
//
#include <hip/hip_runtime.h>
#include <cstddef>
#include <cstdint>

// ---------------------------------------------------------------------------
// AttentionSubsample (LeViT-style), B=64, C=256, H=8, KD=16, D=32,
// N=784 (28x28), N_=196 (14x14), stride 2.
//
// Round 7 == Round 6 resubmit (GPU acquisition timed out; no data).
// Attention re-parallelized (1 wave per (b,h,n-tile), 6656 waves),
// K-dim packed [Kh|Kl] QK^T (2 MFMA, no zero lanes), exp2-domain softmax,
// cvt_pk bf16 P-pack, bias relaid [h][208][784].
// ---------------------------------------------------------------------------

#define SCALE_ATTN2 0.36067376f   // 0.25 * log2(e)
#define LOG2E 1.44269504f
#define BN_EPS 1e-5f

typedef short s8v __attribute__((ext_vector_type(8)));
typedef short s4v __attribute__((ext_vector_type(4)));
typedef float f4v __attribute__((ext_vector_type(4)));

__device__ __forceinline__ float hswish(float y) {
    float t = fminf(fmaxf(y + 3.0f, 0.0f), 6.0f);
    return y * t * (1.0f / 6.0f);
}
__device__ __forceinline__ unsigned short bf16_rn(float f) {
    unsigned u = __float_as_uint(f);
    unsigned r = (u + 0x7FFFu + ((u >> 16) & 1u)) >> 16;
    return (unsigned short)r;
}
__device__ __forceinline__ float bf16_to_f(unsigned short h) {
    return __uint_as_float(((unsigned)h) << 16);
}
__device__ __forceinline__ void gload_lds16(const void* gsrc, void* ldsdst) {
    __builtin_amdgcn_global_load_lds(
        (const __attribute__((address_space(1))) unsigned int*)gsrc,
        (__attribute__((address_space(3))) unsigned int*)ldsdst, 16, 0, 0);
}

// ---------------- W pre-convert: fp32 [o][c] -> bf16 hi/lo ----------------
__global__ __launch_bounds__(256)
void wprep(const float* __restrict__ W, short* __restrict__ hi,
           short* __restrict__ lo, int n4)
{
    int i = blockIdx.x * 256 + threadIdx.x;
    int stride = gridDim.x * 256;
    for (; i < n4; i += stride) {
        float4 v = reinterpret_cast<const float4*>(W)[i];
        s4v h, l;
        unsigned short hh;
        hh = bf16_rn(v.x); h[0] = (short)hh; l[0] = (short)bf16_rn(v.x - bf16_to_f(hh));
        hh = bf16_rn(v.y); h[1] = (short)hh; l[1] = (short)bf16_rn(v.y - bf16_to_f(hh));
        hh = bf16_rn(v.z); h[2] = (short)hh; l[2] = (short)bf16_rn(v.z - bf16_to_f(hh));
        hh = bf16_rn(v.w); h[3] = (short)hh; l[3] = (short)bf16_rn(v.w - bf16_to_f(hh));
        reinterpret_cast<s4v*>(hi)[i] = h;
        reinterpret_cast<s4v*>(lo)[i] = l;
    }
}

// ---------------- x pre-pass: transpose + split + swizzle into tiles -------
__global__ __launch_bounds__(256)
void xprep(const float* __restrict__ x, short* __restrict__ xT)
{
    __shared__ float T[64][65];
    int nt = blockIdx.x, b = blockIdx.y;
    int n0 = nt * 64;
    const float* xb = x + (size_t)b * 256 * 784;
    int t = threadIdx.x;
    int cr = t >> 2, s = t & 3;

    for (int ct = 0; ct < 4; ++ct) {
        __syncthreads();
#pragma unroll
        for (int qq = 0; qq < 4; ++qq) {
            int n = n0 + s * 16 + qq * 4;
            float4 v = make_float4(0.f, 0.f, 0.f, 0.f);
            if (n + 3 < 784)
                v = *reinterpret_cast<const float4*>(&xb[(size_t)(ct * 64 + cr) * 784 + n]);
            *reinterpret_cast<float4*>(&T[cr][s * 16 + qq * 4]) = v;
        }
        __syncthreads();
        int r = cr;
        if (n0 + r < 784) {
            size_t tb = ((((size_t)b * 13 + nt) * 4 + ct) << 13);  // shorts
            short* hiB = xT + tb;
            short* loB = xT + tb + 4096;
            s8v h0, h1, l0, l1;
#pragma unroll
            for (int j = 0; j < 8; ++j) {
                float f = T[s * 16 + j][r];
                unsigned short hh = bf16_rn(f);
                h0[j] = (short)hh; l0[j] = (short)bf16_rn(f - bf16_to_f(hh));
            }
#pragma unroll
            for (int j = 0; j < 8; ++j) {
                float f = T[s * 16 + 8 + j][r];
                unsigned short hh = bf16_rn(f);
                h1[j] = (short)hh; l1[j] = (short)bf16_rn(f - bf16_to_f(hh));
            }
            int sw = (r & 7) << 3;
            int base = r * 64;
            *reinterpret_cast<s8v*>(&hiB[base + ((s * 16) ^ sw)]) = h0;
            *reinterpret_cast<s8v*>(&hiB[base + ((s * 16 + 8) ^ sw)]) = h1;
            *reinterpret_cast<s8v*>(&loB[base + ((s * 16) ^ sw)]) = l0;
            *reinterpret_cast<s8v*>(&loB[base + ((s * 16 + 8) ^ sw)]) = l1;
        }
    }
}

// ---------------- bias precompute: biasF[h][208 n][784 m] = bf16(ab*log2e) -
__global__ __launch_bounds__(256)
void bias_kernel(const float* __restrict__ ab, const int* __restrict__ idxs,
                 unsigned short* __restrict__ biasF, int n_off)
{
    int i = blockIdx.x * 256 + threadIdx.x;   // over 196*784
    if (i < 196 * 784) {
        int id = idxs[i];
        int n = i / 784, m = i - n * 784;
#pragma unroll
        for (int h = 0; h < 8; ++h)
            biasF[((size_t)h * 208 + n) * 784 + m] = bf16_rn(ab[h * n_off + id] * LOG2E);
    }
}

// ---------------- kv GEMM: 128o x 64n, async-staged swizzled B -------------
// channel o -> h = o/48, c = o%48; c<16 -> Kt hi/lo [b][h][m][16];
//                                  c>=16 -> Vbf [b][h][32][m] (d = c-16)
__global__ __launch_bounds__(256)
void gemm_kv(const short* __restrict__ xT,
             const short* __restrict__ Whi, const short* __restrict__ Wlo,
             const float* __restrict__ G, const float* __restrict__ Bb,
             const float* __restrict__ Mm, const float* __restrict__ Vv,
             short* __restrict__ Kthi, short* __restrict__ Ktlo,
             short* __restrict__ Vbf)
{
    __shared__ short Bt[2][64][64];
    __shared__ float scs[128], shs[128];

    int nt = blockIdx.x, oy = blockIdx.y, b = blockIdx.z;
    int oBase = oy * 128;
    int tid = threadIdx.x, w = tid >> 6, l = tid & 63;
    int fr = l & 15, g = l >> 4;

    if (tid < 128) {
        int o = oBase + tid;
        float sc = G[o] * rsqrtf(Vv[o] + BN_EPS);
        scs[tid] = sc; shs[tid] = Bb[o] - Mm[o] * sc;
    }

    f4v acc[2][4];
#pragma unroll
    for (int i = 0; i < 2; ++i)
#pragma unroll
        for (int j = 0; j < 4; ++j) acc[i][j] = (f4v)0.0f;

    const char* tilesrc = (const char*)(xT) + ((((size_t)b * 13 + nt) * 4) << 14);
    char* ldsbase = (char*)&Bt[0][0][0];

    for (int ct = 0; ct < 4; ++ct) {
        __syncthreads();
        {
            const char* src = tilesrc + ((size_t)ct << 14) + w * 4096 + l * 16;
            char* dst = ldsbase + w * 4096;
#pragma unroll
            for (int j = 0; j < 4; ++j)
                gload_lds16(src + j * 1024, dst + j * 1024);
        }
        __syncthreads();
#pragma unroll
        for (int ks = 0; ks < 2; ++ks) {
            s8v ah[2], al[2];
#pragma unroll
            for (int mf = 0; mf < 2; ++mf) {
                int o = oBase + w * 32 + mf * 16 + fr;
                size_t wi = (size_t)o * 256 + ct * 64 + ks * 32 + g * 8;
                ah[mf] = *reinterpret_cast<const s8v*>(&Whi[wi]);
                al[mf] = *reinterpret_cast<const s8v*>(&Wlo[wi]);
            }
#pragma unroll
            for (int nf = 0; nf < 4; ++nf) {
                int r = nf * 16 + fr;
                int ci = (ks * 32 + g * 8) ^ ((r & 7) << 3);
                s8v bh = *reinterpret_cast<const s8v*>(&Bt[0][r][ci]);
                s8v bl = *reinterpret_cast<const s8v*>(&Bt[1][r][ci]);
#pragma unroll
                for (int mf = 0; mf < 2; ++mf) {
                    acc[mf][nf] = __builtin_amdgcn_mfma_f32_16x16x32_bf16(ah[mf], bh, acc[mf][nf], 0, 0, 0);
                    acc[mf][nf] = __builtin_amdgcn_mfma_f32_16x16x32_bf16(ah[mf], bl, acc[mf][nf], 0, 0, 0);
                    acc[mf][nf] = __builtin_amdgcn_mfma_f32_16x16x32_bf16(al[mf], bh, acc[mf][nf], 0, 0, 0);
                }
            }
        }
    }

    int nBase = nt * 64;
#pragma unroll
    for (int mf = 0; mf < 2; ++mf) {
        int ol = w * 32 + mf * 16 + g * 4;    // 4-aligned; run of 4 stays in one (h, K/V) region
        int o = oBase + ol;
        int h = o / 48;
        int c = o - h * 48;
        if (c < 16) {
#pragma unroll
            for (int nf = 0; nf < 4; ++nf) {
                int n = nBase + nf * 16 + fr;
                if (n < 784) {
                    s4v hv, lv;
#pragma unroll
                    for (int e = 0; e < 4; ++e) {
                        float z = hswish(acc[mf][nf][e] * scs[ol + e] + shs[ol + e]);
                        unsigned short hh = bf16_rn(z);
                        hv[e] = (short)hh; lv[e] = (short)bf16_rn(z - bf16_to_f(hh));
                    }
                    size_t ki = (((size_t)b * 8 + h) * 784 + n) * 16 + c;
                    *reinterpret_cast<s4v*>(&Kthi[ki]) = hv;
                    *reinterpret_cast<s4v*>(&Ktlo[ki]) = lv;
                }
            }
        } else {
            int d = c - 16;
#pragma unroll
            for (int nf = 0; nf < 4; ++nf) {
                int n = nBase + nf * 16 + fr;
                if (n < 784) {
#pragma unroll
                    for (int e = 0; e < 4; ++e) {
                        float z = hswish(acc[mf][nf][e] * scs[ol + e] + shs[ol + e]);
                        Vbf[(((size_t)b * 8 + h) * 32 + d + e) * 784 + n] = (short)bf16_rn(z);
                    }
                }
            }
        }
    }
}

// ---------------- q GEMM: 128o x 64n, gather-staged B (strided x) ----------
__global__ __launch_bounds__(256)
void gemm_q(const float* __restrict__ x,
            const short* __restrict__ Whi, const short* __restrict__ Wlo,
            const float* __restrict__ G, const float* __restrict__ Bb,
            const float* __restrict__ Mm, const float* __restrict__ Vv,
            short* __restrict__ Qthi, short* __restrict__ Qtlo)
{
    __shared__ short Bt[2][64][64];
    __shared__ float scs[128], shs[128];

    int nt = blockIdx.x, b = blockIdx.z;
    const float* xb = x + (size_t)b * 256 * 784;
    int tid = threadIdx.x, w = tid >> 6, l = tid & 63;
    int fr = l & 15, g = l >> 4;
    int sr = tid >> 4, sc4 = (tid & 15) * 4;

    if (tid < 128) {
        int o = tid;
        float sc = G[o] * rsqrtf(Vv[o] + BN_EPS);
        scs[tid] = sc; shs[tid] = Bb[o] - Mm[o] * sc;
    }

    f4v acc[2][4];
#pragma unroll
    for (int i = 0; i < 2; ++i)
#pragma unroll
        for (int j = 0; j < 4; ++j) acc[i][j] = (f4v)0.0f;

    for (int ct = 0; ct < 4; ++ct) {
        __syncthreads();
#pragma unroll
        for (int jc = 0; jc < 4; ++jc) {
            int c = sr + jc * 16;
#pragma unroll
            for (int e = 0; e < 4; ++e) {
                int nn = nt * 64 + sc4 + e;
                float v = 0.0f;
                if (nn < 196) {
                    int rr = nn / 14, cc = nn - rr * 14;
                    v = xb[(size_t)(ct * 64 + c) * 784 + rr * 56 + cc * 2];
                }
                int r = sc4 + e;
                int ci = c ^ ((r & 7) << 3);
                unsigned short hh = bf16_rn(v);
                Bt[0][r][ci] = (short)hh;
                Bt[1][r][ci] = (short)bf16_rn(v - bf16_to_f(hh));
            }
        }
        __syncthreads();
#pragma unroll
        for (int ks = 0; ks < 2; ++ks) {
            s8v ah[2], al[2];
#pragma unroll
            for (int mf = 0; mf < 2; ++mf) {
                int o = w * 32 + mf * 16 + fr;
                size_t wi = (size_t)o * 256 + ct * 64 + ks * 32 + g * 8;
                ah[mf] = *reinterpret_cast<const s8v*>(&Whi[wi]);
                al[mf] = *reinterpret_cast<const s8v*>(&Wlo[wi]);
            }
#pragma unroll
            for (int nf = 0; nf < 4; ++nf) {
                int r = nf * 16 + fr;
                int ci = (ks * 32 + g * 8) ^ ((r & 7) << 3);
                s8v bh = *reinterpret_cast<const s8v*>(&Bt[0][r][ci]);
                s8v bl = *reinterpret_cast<const s8v*>(&Bt[1][r][ci]);
#pragma unroll
                for (int mf = 0; mf < 2; ++mf) {
                    acc[mf][nf] = __builtin_amdgcn_mfma_f32_16x16x32_bf16(ah[mf], bh, acc[mf][nf], 0, 0, 0);
                    acc[mf][nf] = __builtin_amdgcn_mfma_f32_16x16x32_bf16(ah[mf], bl, acc[mf][nf], 0, 0, 0);
                    acc[mf][nf] = __builtin_amdgcn_mfma_f32_16x16x32_bf16(al[mf], bh, acc[mf][nf], 0, 0, 0);
                }
            }
        }
    }

#pragma unroll
    for (int mf = 0; mf < 2; ++mf) {
        int ol = w * 32 + mf * 16 + g * 4;
        int h = ol >> 4, d0 = ol & 15;
#pragma unroll
        for (int nf = 0; nf < 4; ++nf) {
            int n = nt * 64 + nf * 16 + fr;
            if (n < 196) {
                s4v hv, lv;
#pragma unroll
                for (int e = 0; e < 4; ++e) {
                    float z = hswish(acc[mf][nf][e] * scs[ol + e] + shs[ol + e]);
                    unsigned short hh = bf16_rn(z);
                    hv[e] = (short)hh; lv[e] = (short)bf16_rn(z - bf16_to_f(hh));
                }
                size_t qi = (((size_t)b * 8 + h) * 196 + n) * 16 + d0;
                *reinterpret_cast<s4v*>(&Qthi[qi]) = hv;
                *reinterpret_cast<s4v*>(&Qtlo[qi]) = lv;
            }
        }
    }
}

// ---------------- attention: 1 wave per (b,h,tile), direct-global ----------
// QK^T K-packed: A=[Kh|Kl] (K=32), B1=[Qh|Qh] -> Kh.Qh+Kl.Qh; B2=[Ql|0] -> Kh.Ql
// Softmax in exp2 domain (bias pre-scaled by log2e). P packed via v_cvt_pk_bf16.
__global__ __launch_bounds__(256, 8)
void attn_mfma(const short* __restrict__ Kthi, const short* __restrict__ Ktlo,
               const short* __restrict__ Vbf,
               const short* __restrict__ Qthi, const short* __restrict__ Qtlo,
               const unsigned short* __restrict__ biasF, short* __restrict__ actT)
{
    __shared__ short Pl[4][16][72];

    int tid = threadIdx.x, w = tid >> 6, l = tid & 63;
    int idx = blockIdx.x * 4 + w;            // < 6656 = 512*13
    int bh = idx / 13, tile = idx - bh * 13;
    int b = bh >> 3, h = bh & 7;
    int g = l >> 4, fr = l & 15;

    const short* Kbase = ((g < 2) ? Kthi : Ktlo) + (size_t)bh * 784 * 16;
    const short* Vb = Vbf + (size_t)bh * 32 * 784;
    const short* Qh = Qthi + (size_t)bh * 196 * 16;
    const short* Ql = Qtlo + (size_t)bh * 196 * 16;
    int n = tile * 16 + fr;                   // may be >=196 on tile 12 (discarded)
    const unsigned short* bB = biasF + ((size_t)h * 208 + n) * 784;

    // Q fragments: qf1 = [Qh|Qh], qf2 = [Ql|0]
    s8v qf1 = (s8v)0, qf2 = (s8v)0;
    if (n < 196) {
        qf1 = *reinterpret_cast<const s8v*>(&Qh[(size_t)n * 16 + (g & 1) * 8]);
        if (g < 2) qf2 = *reinterpret_cast<const s8v*>(&Ql[(size_t)n * 16 + g * 8]);
    }

    f4v Oa0 = (f4v)0.0f, Oa1 = (f4v)0.0f;
    float M = -1e30f, L = 0.0f;

#pragma unroll 1
    for (int ch = 0; ch < 13; ++ch) {
        int m0 = ch * 64;
        int subLim = (ch == 12) ? 1 : 4;
        int mlim = (ch == 12) ? 16 : 64;

        float s[4][4];
#pragma unroll
        for (int sub = 0; sub < 4; ++sub) {
            if (sub < subLim) {
                int mg = m0 + sub * 16 + fr;
                s8v af = *reinterpret_cast<const s8v*>(&Kbase[(size_t)mg * 16 + (g & 1) * 8]);
                f4v a = (f4v)0.0f;
                a = __builtin_amdgcn_mfma_f32_16x16x32_bf16(af, qf1, a, 0, 0, 0);
                a = __builtin_amdgcn_mfma_f32_16x16x32_bf16(af, qf2, a, 0, 0, 0);
                s4v bv = *reinterpret_cast<const s4v*>(&bB[m0 + sub * 16 + g * 4]);
#pragma unroll
                for (int e = 0; e < 4; ++e)
                    s[sub][e] = a[e] * SCALE_ATTN2 + bf16_to_f((unsigned short)bv[e]);
            } else {
#pragma unroll
                for (int e = 0; e < 4; ++e) s[sub][e] = -1e30f;
            }
        }

        // max over lane's 16 + cross-g
        float mx = fmaxf(fmaxf(fmaxf(s[0][0], s[0][1]), fmaxf(s[0][2], s[0][3])),
                         fmaxf(fmaxf(s[1][0], s[1][1]), fmaxf(s[1][2], s[1][3])));
        mx = fmaxf(mx, fmaxf(fmaxf(fmaxf(s[2][0], s[2][1]), fmaxf(s[2][2], s[2][3])),
                             fmaxf(fmaxf(s[3][0], s[3][1]), fmaxf(s[3][2], s[3][3]))));
        mx = fmaxf(mx, __shfl_xor(mx, 16));
        mx = fmaxf(mx, __shfl_xor(mx, 32));
        if (__any(mx > M + 8.0f)) {           // defer-max (log2 domain)
            float Mn = fmaxf(M, mx);
            float corr = exp2f(M - Mn);
            L *= corr;
#pragma unroll
            for (int e = 0; e < 4; ++e) { Oa0[e] *= corr; Oa1[e] *= corr; }
            M = Mn;
        }

        float Ls = 0.0f;
#pragma unroll
        for (int sub = 0; sub < 4; ++sub) {
            float p[4];
#pragma unroll
            for (int e = 0; e < 4; ++e) {
                int mml = sub * 16 + g * 4 + e;
                float pv = exp2f(s[sub][e] - M);
                p[e] = (mml < mlim) ? pv : 0.0f;
                Ls += p[e];
            }
            unsigned w0, w1;
            asm("v_cvt_pk_bf16_f32 %0, %1, %2" : "=v"(w0) : "v"(p[0]), "v"(p[1]));
            asm("v_cvt_pk_bf16_f32 %0, %1, %2" : "=v"(w1) : "v"(p[2]), "v"(p[3]));
            int mb = sub * 16 + g * 4;
            *reinterpret_cast<unsigned*>(&Pl[w][fr][mb]) = w0;
            *reinterpret_cast<unsigned*>(&Pl[w][fr][mb + 2]) = w1;
        }
        Ls += __shfl_xor(Ls, 16);
        Ls += __shfl_xor(Ls, 32);
        L += Ls;

#pragma unroll
        for (int kc = 0; kc < 2; ++kc) {
            s8v pf = *reinterpret_cast<const s8v*>(&Pl[w][fr][kc * 32 + g * 8]);
            int mf0 = m0 + kc * 32 + g * 8;
            s8v v0 = (s8v)0, v1 = (s8v)0;
            if (mf0 + 8 <= 784) {
                v0 = *reinterpret_cast<const s8v*>(&Vb[(size_t)fr * 784 + mf0]);
                v1 = *reinterpret_cast<const s8v*>(&Vb[(size_t)(16 + fr) * 784 + mf0]);
            }
            Oa0 = __builtin_amdgcn_mfma_f32_16x16x32_bf16(v0, pf, Oa0, 0, 0, 0);
            Oa1 = __builtin_amdgcn_mfma_f32_16x16x32_bf16(v1, pf, Oa1, 0, 0, 0);
        }
    }

    // epilogue -> actT swizzled hi/lo tiles
    if (n < 196) {
        float inv = 1.0f / L;
        int r = n & 63, ntl = n >> 6;
        int sw = (r & 7) << 3;
#pragma unroll
        for (int dt = 0; dt < 2; ++dt) {
            int c0 = h * 32 + dt * 16 + g * 4;
            f4v* Op = dt ? &Oa1 : &Oa0;
            s4v hv, lv;
#pragma unroll
            for (int e = 0; e < 4; ++e) {
                float z = hswish((*Op)[e] * inv);
                unsigned short hh = bf16_rn(z);
                hv[e] = (short)hh; lv[e] = (short)bf16_rn(z - bf16_to_f(hh));
            }
            int ct = c0 >> 6, c2 = c0 & 63;
            size_t tb = ((((size_t)b * 4 + ntl) * 4 + ct) << 13);  // shorts
            int idx2 = r * 64 + (c2 ^ sw);
            *reinterpret_cast<s4v*>(&actT[tb + idx2]) = hv;
            *reinterpret_cast<s4v*>(&actT[tb + 4096 + idx2]) = lv;
        }
    }
}

// ---------------- proj GEMM: 128o x 64n from actT tiles -> fp32 out --------
__global__ __launch_bounds__(256)
void gemm_proj(const short* __restrict__ actT,
               const short* __restrict__ Whi, const short* __restrict__ Wlo,
               const float* __restrict__ G, const float* __restrict__ Bb,
               const float* __restrict__ Mm, const float* __restrict__ Vv,
               float* __restrict__ out)
{
    __shared__ short Bt[2][64][64];
    __shared__ float scs[128], shs[128];

    int nt = blockIdx.x, oy = blockIdx.y, b = blockIdx.z;
    int oBase = oy * 128;
    int tid = threadIdx.x, w = tid >> 6, l = tid & 63;
    int fr = l & 15, g = l >> 4;

    if (tid < 128) {
        int o = oBase + tid;
        float sc = G[o] * rsqrtf(Vv[o] + BN_EPS);
        scs[tid] = sc; shs[tid] = Bb[o] - Mm[o] * sc;
    }

    f4v acc[2][4];
#pragma unroll
    for (int i = 0; i < 2; ++i)
#pragma unroll
        for (int j = 0; j < 4; ++j) acc[i][j] = (f4v)0.0f;

    const char* tilesrc = (const char*)(actT) + ((((size_t)b * 4 + nt) * 4) << 14);
    char* ldsbase = (char*)&Bt[0][0][0];

    for (int ct = 0; ct < 4; ++ct) {
        __syncthreads();
        {
            const char* src = tilesrc + ((size_t)ct << 14) + w * 4096 + l * 16;
            char* dst = ldsbase + w * 4096;
#pragma unroll
            for (int j = 0; j < 4; ++j)
                gload_lds16(src + j * 1024, dst + j * 1024);
        }
        __syncthreads();
#pragma unroll
        for (int ks = 0; ks < 2; ++ks) {
            s8v ah[2], al[2];
#pragma unroll
            for (int mf = 0; mf < 2; ++mf) {
                int o = oBase + w * 32 + mf * 16 + fr;
                size_t wi = (size_t)o * 256 + ct * 64 + ks * 32 + g * 8;
                ah[mf] = *reinterpret_cast<const s8v*>(&Whi[wi]);
                al[mf] = *reinterpret_cast<const s8v*>(&Wlo[wi]);
            }
#pragma unroll
            for (int nf = 0; nf < 4; ++nf) {
                int r = nf * 16 + fr;
                int ci = (ks * 32 + g * 8) ^ ((r & 7) << 3);
                s8v bh = *reinterpret_cast<const s8v*>(&Bt[0][r][ci]);
                s8v bl = *reinterpret_cast<const s8v*>(&Bt[1][r][ci]);
#pragma unroll
                for (int mf = 0; mf < 2; ++mf) {
                    acc[mf][nf] = __builtin_amdgcn_mfma_f32_16x16x32_bf16(ah[mf], bh, acc[mf][nf], 0, 0, 0);
                    acc[mf][nf] = __builtin_amdgcn_mfma_f32_16x16x32_bf16(ah[mf], bl, acc[mf][nf], 0, 0, 0);
                    acc[mf][nf] = __builtin_amdgcn_mfma_f32_16x16x32_bf16(al[mf], bh, acc[mf][nf], 0, 0, 0);
                }
            }
        }
    }

#pragma unroll
    for (int mf = 0; mf < 2; ++mf) {
        int ol = w * 32 + mf * 16 + g * 4;
#pragma unroll
        for (int nf = 0; nf < 4; ++nf) {
            int n = nt * 64 + nf * 16 + fr;
            if (n < 196) {
#pragma unroll
                for (int e = 0; e < 4; ++e) {
                    float z = hswish(acc[mf][nf][e] * scs[ol + e] + shs[ol + e]);
                    out[((size_t)b * 512 + oBase + ol + e) * 196 + n] = z;
                }
            }
        }
    }
}

// ---------------------------------------------------------------------------
extern "C" void kernel_launch(void* const* d_in, const int* in_sizes, int n_in,
                              void* d_out, int out_size, void* d_ws, size_t ws_size,
                              hipStream_t stream) {
    const float* x      = (const float*)d_in[0];
    const float* kv_w   = (const float*)d_in[1];
    const float* kv_g   = (const float*)d_in[2];
    const float* kv_b   = (const float*)d_in[3];
    const float* kv_m   = (const float*)d_in[4];
    const float* kv_v   = (const float*)d_in[5];
    const float* q_w    = (const float*)d_in[6];
    const float* q_g    = (const float*)d_in[7];
    const float* q_b    = (const float*)d_in[8];
    const float* q_m    = (const float*)d_in[9];
    const float* q_v    = (const float*)d_in[10];
    const float* proj_w = (const float*)d_in[11];
    const float* proj_g = (const float*)d_in[12];
    const float* proj_b = (const float*)d_in[13];
    const float* proj_m = (const float*)d_in[14];
    const float* proj_v = (const float*)d_in[15];
    const float* ab     = (const float*)d_in[16];
    const int*   idxs   = (const int*)d_in[17];
    float* out = (float*)d_out;

    int n_off = in_sizes[16] / 8;

    // ---- workspace layout (bytes, 256-aligned) ----
    char* p = (char*)d_ws;
    size_t off = 0;
    auto alloc = [&](size_t bytes) -> char* {
        char* r = p + off;
        off += (bytes + 255) & ~(size_t)255;
        return r;
    };
    short* Kthi = (short*)alloc((size_t)64 * 8 * 784 * 16 * 2);
    short* Ktlo = (short*)alloc((size_t)64 * 8 * 784 * 16 * 2);
    short* Vbf  = (short*)alloc((size_t)64 * 8 * 32 * 784 * 2);
    short* Qthi = (short*)alloc((size_t)64 * 8 * 196 * 16 * 2);
    short* Qtlo = (short*)alloc((size_t)64 * 8 * 196 * 16 * 2);
    unsigned short* biasF = (unsigned short*)alloc((size_t)8 * 208 * 784 * 2);
    short* Wkvh = (short*)alloc((size_t)384 * 256 * 2);
    short* Wkvl = (short*)alloc((size_t)384 * 256 * 2);
    short* Wqh  = (short*)alloc((size_t)128 * 256 * 2);
    short* Wql  = (short*)alloc((size_t)128 * 256 * 2);
    short* Wpjh = (short*)alloc((size_t)512 * 256 * 2);
    short* Wpjl = (short*)alloc((size_t)512 * 256 * 2);
    short* xT   = (short*)alloc((size_t)64 * 13 * 4 * 16384);
    short* actT = xT;   // alias: xT consumed by gemm_kv before attn writes actT

    // 1. W pre-converts
    wprep<<<dim3(64), 256, 0, stream>>>(kv_w, Wkvh, Wkvl, 384 * 256 / 4);
    wprep<<<dim3(64), 256, 0, stream>>>(q_w, Wqh, Wql, 128 * 256 / 4);
    wprep<<<dim3(64), 256, 0, stream>>>(proj_w, Wpjh, Wpjl, 512 * 256 / 4);
    // 2. x transpose/convert/swizzle tiles
    xprep<<<dim3(13, 64), 256, 0, stream>>>(x, xT);
    // 3. bias gather (bf16, [h][208][784], pre-scaled by log2e)
    bias_kernel<<<dim3((196 * 784 + 255) / 256), 256, 0, stream>>>(ab, idxs, biasF, n_off);
    // 4. kv GEMM -> Kt hi/lo + Vbf
    gemm_kv<<<dim3(13, 3, 64), 256, 0, stream>>>(xT, Wkvh, Wkvl, kv_g, kv_b, kv_m, kv_v,
                                                 Kthi, Ktlo, Vbf);
    // 5. q GEMM -> Qt hi/lo
    gemm_q<<<dim3(4, 1, 64), 256, 0, stream>>>(x, Wqh, Wql, q_g, q_b, q_m, q_v,
                                               Qthi, Qtlo);
    // 6. attention: 1 wave per (bh, tile) -> actT tiles
    attn_mfma<<<dim3(512 * 13 / 4), 256, 0, stream>>>(Kthi, Ktlo, Vbf, Qthi, Qtlo, biasF, actT);
    // 7. proj GEMM -> out
    gemm_proj<<<dim3(4, 4, 64), 256, 0, stream>>>(actT, Wpjh, Wpjl,
                                                  proj_g, proj_b, proj_m, proj_v, out);
}

// Round 9
// 322.091 us; speedup vs baseline: 1.3956x; 1.2038x over previous
//
#include <hip/hip_runtime.h>
#include <cstddef>
#include <cstdint>

// ---------------------------------------------------------------------------
// AttentionSubsample (LeViT-style), B=64, C=256, H=8, KD=16, D=32,
// N=784 (28x28), N_=196 (14x14), stride 2.
//
// Round 8: attention waves process 2 n-tiles each (shared K/V fragment loads,
// 2x ILP), XCD-bijective block swizzle for per-XCD L2 K/V reuse, bias tail
// rows zeroed. 7 waves per (b,h), 896 blocks.
// ---------------------------------------------------------------------------

#define SCALE_ATTN2 0.36067376f   // 0.25 * log2(e)
#define LOG2E 1.44269504f
#define BN_EPS 1e-5f

typedef short s8v __attribute__((ext_vector_type(8)));
typedef short s4v __attribute__((ext_vector_type(4)));
typedef float f4v __attribute__((ext_vector_type(4)));

__device__ __forceinline__ float hswish(float y) {
    float t = fminf(fmaxf(y + 3.0f, 0.0f), 6.0f);
    return y * t * (1.0f / 6.0f);
}
__device__ __forceinline__ unsigned short bf16_rn(float f) {
    unsigned u = __float_as_uint(f);
    unsigned r = (u + 0x7FFFu + ((u >> 16) & 1u)) >> 16;
    return (unsigned short)r;
}
__device__ __forceinline__ float bf16_to_f(unsigned short h) {
    return __uint_as_float(((unsigned)h) << 16);
}
__device__ __forceinline__ void gload_lds16(const void* gsrc, void* ldsdst) {
    __builtin_amdgcn_global_load_lds(
        (const __attribute__((address_space(1))) unsigned int*)gsrc,
        (__attribute__((address_space(3))) unsigned int*)ldsdst, 16, 0, 0);
}

// ---------------- W pre-convert: fp32 [o][c] -> bf16 hi/lo ----------------
__global__ __launch_bounds__(256)
void wprep(const float* __restrict__ W, short* __restrict__ hi,
           short* __restrict__ lo, int n4)
{
    int i = blockIdx.x * 256 + threadIdx.x;
    int stride = gridDim.x * 256;
    for (; i < n4; i += stride) {
        float4 v = reinterpret_cast<const float4*>(W)[i];
        s4v h, l;
        unsigned short hh;
        hh = bf16_rn(v.x); h[0] = (short)hh; l[0] = (short)bf16_rn(v.x - bf16_to_f(hh));
        hh = bf16_rn(v.y); h[1] = (short)hh; l[1] = (short)bf16_rn(v.y - bf16_to_f(hh));
        hh = bf16_rn(v.z); h[2] = (short)hh; l[2] = (short)bf16_rn(v.z - bf16_to_f(hh));
        hh = bf16_rn(v.w); h[3] = (short)hh; l[3] = (short)bf16_rn(v.w - bf16_to_f(hh));
        reinterpret_cast<s4v*>(hi)[i] = h;
        reinterpret_cast<s4v*>(lo)[i] = l;
    }
}

// ---------------- x pre-pass: transpose + split + swizzle into tiles -------
__global__ __launch_bounds__(256)
void xprep(const float* __restrict__ x, short* __restrict__ xT)
{
    __shared__ float T[64][65];
    int nt = blockIdx.x, b = blockIdx.y;
    int n0 = nt * 64;
    const float* xb = x + (size_t)b * 256 * 784;
    int t = threadIdx.x;
    int cr = t >> 2, s = t & 3;

    for (int ct = 0; ct < 4; ++ct) {
        __syncthreads();
#pragma unroll
        for (int qq = 0; qq < 4; ++qq) {
            int n = n0 + s * 16 + qq * 4;
            float4 v = make_float4(0.f, 0.f, 0.f, 0.f);
            if (n + 3 < 784)
                v = *reinterpret_cast<const float4*>(&xb[(size_t)(ct * 64 + cr) * 784 + n]);
            *reinterpret_cast<float4*>(&T[cr][s * 16 + qq * 4]) = v;
        }
        __syncthreads();
        int r = cr;
        if (n0 + r < 784) {
            size_t tb = ((((size_t)b * 13 + nt) * 4 + ct) << 13);  // shorts
            short* hiB = xT + tb;
            short* loB = xT + tb + 4096;
            s8v h0, h1, l0, l1;
#pragma unroll
            for (int j = 0; j < 8; ++j) {
                float f = T[s * 16 + j][r];
                unsigned short hh = bf16_rn(f);
                h0[j] = (short)hh; l0[j] = (short)bf16_rn(f - bf16_to_f(hh));
            }
#pragma unroll
            for (int j = 0; j < 8; ++j) {
                float f = T[s * 16 + 8 + j][r];
                unsigned short hh = bf16_rn(f);
                h1[j] = (short)hh; l1[j] = (short)bf16_rn(f - bf16_to_f(hh));
            }
            int sw = (r & 7) << 3;
            int base = r * 64;
            *reinterpret_cast<s8v*>(&hiB[base + ((s * 16) ^ sw)]) = h0;
            *reinterpret_cast<s8v*>(&hiB[base + ((s * 16 + 8) ^ sw)]) = h1;
            *reinterpret_cast<s8v*>(&loB[base + ((s * 16) ^ sw)]) = l0;
            *reinterpret_cast<s8v*>(&loB[base + ((s * 16 + 8) ^ sw)]) = l1;
        }
    }
}

// ---------------- bias precompute: biasF[h][208 n][784 m] = bf16(ab*log2e) -
// rows 196..207 zero-filled (read by the tail wave, never stored)
__global__ __launch_bounds__(256)
void bias_kernel(const float* __restrict__ ab, const int* __restrict__ idxs,
                 unsigned short* __restrict__ biasF, int n_off)
{
    int i = blockIdx.x * 256 + threadIdx.x;   // over 208*784
    if (i < 208 * 784) {
        int n = i / 784, m = i - n * 784;
        if (n < 196) {
            int id = idxs[i];
#pragma unroll
            for (int h = 0; h < 8; ++h)
                biasF[((size_t)h * 208 + n) * 784 + m] = bf16_rn(ab[h * n_off + id] * LOG2E);
        } else {
#pragma unroll
            for (int h = 0; h < 8; ++h)
                biasF[((size_t)h * 208 + n) * 784 + m] = 0;
        }
    }
}

// ---------------- kv GEMM: 128o x 64n, async-staged swizzled B -------------
// channel o -> h = o/48, c = o%48; c<16 -> Kt hi/lo [b][h][m][16];
//                                  c>=16 -> Vbf [b][h][32][m] (d = c-16)
__global__ __launch_bounds__(256)
void gemm_kv(const short* __restrict__ xT,
             const short* __restrict__ Whi, const short* __restrict__ Wlo,
             const float* __restrict__ G, const float* __restrict__ Bb,
             const float* __restrict__ Mm, const float* __restrict__ Vv,
             short* __restrict__ Kthi, short* __restrict__ Ktlo,
             short* __restrict__ Vbf)
{
    __shared__ short Bt[2][64][64];
    __shared__ float scs[128], shs[128];

    int nt = blockIdx.x, oy = blockIdx.y, b = blockIdx.z;
    int oBase = oy * 128;
    int tid = threadIdx.x, w = tid >> 6, l = tid & 63;
    int fr = l & 15, g = l >> 4;

    if (tid < 128) {
        int o = oBase + tid;
        float sc = G[o] * rsqrtf(Vv[o] + BN_EPS);
        scs[tid] = sc; shs[tid] = Bb[o] - Mm[o] * sc;
    }

    f4v acc[2][4];
#pragma unroll
    for (int i = 0; i < 2; ++i)
#pragma unroll
        for (int j = 0; j < 4; ++j) acc[i][j] = (f4v)0.0f;

    const char* tilesrc = (const char*)(xT) + ((((size_t)b * 13 + nt) * 4) << 14);
    char* ldsbase = (char*)&Bt[0][0][0];

    for (int ct = 0; ct < 4; ++ct) {
        __syncthreads();
        {
            const char* src = tilesrc + ((size_t)ct << 14) + w * 4096 + l * 16;
            char* dst = ldsbase + w * 4096;
#pragma unroll
            for (int j = 0; j < 4; ++j)
                gload_lds16(src + j * 1024, dst + j * 1024);
        }
        __syncthreads();
#pragma unroll
        for (int ks = 0; ks < 2; ++ks) {
            s8v ah[2], al[2];
#pragma unroll
            for (int mf = 0; mf < 2; ++mf) {
                int o = oBase + w * 32 + mf * 16 + fr;
                size_t wi = (size_t)o * 256 + ct * 64 + ks * 32 + g * 8;
                ah[mf] = *reinterpret_cast<const s8v*>(&Whi[wi]);
                al[mf] = *reinterpret_cast<const s8v*>(&Wlo[wi]);
            }
#pragma unroll
            for (int nf = 0; nf < 4; ++nf) {
                int r = nf * 16 + fr;
                int ci = (ks * 32 + g * 8) ^ ((r & 7) << 3);
                s8v bh = *reinterpret_cast<const s8v*>(&Bt[0][r][ci]);
                s8v bl = *reinterpret_cast<const s8v*>(&Bt[1][r][ci]);
#pragma unroll
                for (int mf = 0; mf < 2; ++mf) {
                    acc[mf][nf] = __builtin_amdgcn_mfma_f32_16x16x32_bf16(ah[mf], bh, acc[mf][nf], 0, 0, 0);
                    acc[mf][nf] = __builtin_amdgcn_mfma_f32_16x16x32_bf16(ah[mf], bl, acc[mf][nf], 0, 0, 0);
                    acc[mf][nf] = __builtin_amdgcn_mfma_f32_16x16x32_bf16(al[mf], bh, acc[mf][nf], 0, 0, 0);
                }
            }
        }
    }

    int nBase = nt * 64;
#pragma unroll
    for (int mf = 0; mf < 2; ++mf) {
        int ol = w * 32 + mf * 16 + g * 4;    // 4-aligned; run of 4 stays in one (h, K/V) region
        int o = oBase + ol;
        int h = o / 48;
        int c = o - h * 48;
        if (c < 16) {
#pragma unroll
            for (int nf = 0; nf < 4; ++nf) {
                int n = nBase + nf * 16 + fr;
                if (n < 784) {
                    s4v hv, lv;
#pragma unroll
                    for (int e = 0; e < 4; ++e) {
                        float z = hswish(acc[mf][nf][e] * scs[ol + e] + shs[ol + e]);
                        unsigned short hh = bf16_rn(z);
                        hv[e] = (short)hh; lv[e] = (short)bf16_rn(z - bf16_to_f(hh));
                    }
                    size_t ki = (((size_t)b * 8 + h) * 784 + n) * 16 + c;
                    *reinterpret_cast<s4v*>(&Kthi[ki]) = hv;
                    *reinterpret_cast<s4v*>(&Ktlo[ki]) = lv;
                }
            }
        } else {
            int d = c - 16;
#pragma unroll
            for (int nf = 0; nf < 4; ++nf) {
                int n = nBase + nf * 16 + fr;
                if (n < 784) {
#pragma unroll
                    for (int e = 0; e < 4; ++e) {
                        float z = hswish(acc[mf][nf][e] * scs[ol + e] + shs[ol + e]);
                        Vbf[(((size_t)b * 8 + h) * 32 + d + e) * 784 + n] = (short)bf16_rn(z);
                    }
                }
            }
        }
    }
}

// ---------------- q GEMM: 128o x 64n, gather-staged B (strided x) ----------
__global__ __launch_bounds__(256)
void gemm_q(const float* __restrict__ x,
            const short* __restrict__ Whi, const short* __restrict__ Wlo,
            const float* __restrict__ G, const float* __restrict__ Bb,
            const float* __restrict__ Mm, const float* __restrict__ Vv,
            short* __restrict__ Qthi, short* __restrict__ Qtlo)
{
    __shared__ short Bt[2][64][64];
    __shared__ float scs[128], shs[128];

    int nt = blockIdx.x, b = blockIdx.z;
    const float* xb = x + (size_t)b * 256 * 784;
    int tid = threadIdx.x, w = tid >> 6, l = tid & 63;
    int fr = l & 15, g = l >> 4;
    int sr = tid >> 4, sc4 = (tid & 15) * 4;

    if (tid < 128) {
        int o = tid;
        float sc = G[o] * rsqrtf(Vv[o] + BN_EPS);
        scs[tid] = sc; shs[tid] = Bb[o] - Mm[o] * sc;
    }

    f4v acc[2][4];
#pragma unroll
    for (int i = 0; i < 2; ++i)
#pragma unroll
        for (int j = 0; j < 4; ++j) acc[i][j] = (f4v)0.0f;

    for (int ct = 0; ct < 4; ++ct) {
        __syncthreads();
#pragma unroll
        for (int jc = 0; jc < 4; ++jc) {
            int c = sr + jc * 16;
#pragma unroll
            for (int e = 0; e < 4; ++e) {
                int nn = nt * 64 + sc4 + e;
                float v = 0.0f;
                if (nn < 196) {
                    int rr = nn / 14, cc = nn - rr * 14;
                    v = xb[(size_t)(ct * 64 + c) * 784 + rr * 56 + cc * 2];
                }
                int r = sc4 + e;
                int ci = c ^ ((r & 7) << 3);
                unsigned short hh = bf16_rn(v);
                Bt[0][r][ci] = (short)hh;
                Bt[1][r][ci] = (short)bf16_rn(v - bf16_to_f(hh));
            }
        }
        __syncthreads();
#pragma unroll
        for (int ks = 0; ks < 2; ++ks) {
            s8v ah[2], al[2];
#pragma unroll
            for (int mf = 0; mf < 2; ++mf) {
                int o = w * 32 + mf * 16 + fr;
                size_t wi = (size_t)o * 256 + ct * 64 + ks * 32 + g * 8;
                ah[mf] = *reinterpret_cast<const s8v*>(&Whi[wi]);
                al[mf] = *reinterpret_cast<const s8v*>(&Wlo[wi]);
            }
#pragma unroll
            for (int nf = 0; nf < 4; ++nf) {
                int r = nf * 16 + fr;
                int ci = (ks * 32 + g * 8) ^ ((r & 7) << 3);
                s8v bh = *reinterpret_cast<const s8v*>(&Bt[0][r][ci]);
                s8v bl = *reinterpret_cast<const s8v*>(&Bt[1][r][ci]);
#pragma unroll
                for (int mf = 0; mf < 2; ++mf) {
                    acc[mf][nf] = __builtin_amdgcn_mfma_f32_16x16x32_bf16(ah[mf], bh, acc[mf][nf], 0, 0, 0);
                    acc[mf][nf] = __builtin_amdgcn_mfma_f32_16x16x32_bf16(ah[mf], bl, acc[mf][nf], 0, 0, 0);
                    acc[mf][nf] = __builtin_amdgcn_mfma_f32_16x16x32_bf16(al[mf], bh, acc[mf][nf], 0, 0, 0);
                }
            }
        }
    }

#pragma unroll
    for (int mf = 0; mf < 2; ++mf) {
        int ol = w * 32 + mf * 16 + g * 4;
        int h = ol >> 4, d0 = ol & 15;
#pragma unroll
        for (int nf = 0; nf < 4; ++nf) {
            int n = nt * 64 + nf * 16 + fr;
            if (n < 196) {
                s4v hv, lv;
#pragma unroll
                for (int e = 0; e < 4; ++e) {
                    float z = hswish(acc[mf][nf][e] * scs[ol + e] + shs[ol + e]);
                    unsigned short hh = bf16_rn(z);
                    hv[e] = (short)hh; lv[e] = (short)bf16_rn(z - bf16_to_f(hh));
                }
                size_t qi = (((size_t)b * 8 + h) * 196 + n) * 16 + d0;
                *reinterpret_cast<s4v*>(&Qthi[qi]) = hv;
                *reinterpret_cast<s4v*>(&Qtlo[qi]) = lv;
            }
        }
    }
}

// ---------------- attention: 1 wave per (b,h,tile-pair) --------------------
// 7 waves per (b,h): waves j=0..5 own tiles (2j, 2j+1); j=6 owns tile 12.
// Shared K/V fragment loads feed both tiles' MFMA chains (2x ILP).
// XCD-bijective swizzle: 896 blocks = 8 x 112.
__global__ __launch_bounds__(256, 4)
void attn_mfma(const short* __restrict__ Kthi, const short* __restrict__ Ktlo,
               const short* __restrict__ Vbf,
               const short* __restrict__ Qthi, const short* __restrict__ Qtlo,
               const unsigned short* __restrict__ biasF, short* __restrict__ actT)
{
    __shared__ short Pl[4][2][16][72];

    int tid = threadIdx.x, w = tid >> 6, l = tid & 63;
    int lb = (blockIdx.x & 7) * 112 + (blockIdx.x >> 3);   // XCD-contiguous
    int idx = lb * 4 + w;                // < 3584 = 512*7
    int bh = idx / 7, j = idx - bh * 7;
    int b = bh >> 3, h = bh & 7;
    int g = l >> 4, fr = l & 15;
    bool two = (j < 6);
    int n0 = (2 * j) * 16 + fr;          // j=6 -> 192..207 (195 max valid)
    int n1 = two ? (n0 + 16) : n0;       // always <=191 when two

    const short* Kbase = ((g < 2) ? Kthi : Ktlo) + (size_t)bh * 784 * 16;
    const short* Vb = Vbf + (size_t)bh * 32 * 784;
    const short* Qh = Qthi + (size_t)bh * 196 * 16;
    const short* Ql = Qtlo + (size_t)bh * 196 * 16;
    const unsigned short* bB0 = biasF + ((size_t)h * 208 + n0) * 784;
    const unsigned short* bB1 = biasF + ((size_t)h * 208 + n1) * 784;

    // Q fragments: qA = [Qh|Qh] (vs K hi/lo), qB = [Ql|0] (vs K hi)
    s8v qA0 = (s8v)0, qB0 = (s8v)0, qA1 = (s8v)0, qB1 = (s8v)0;
    if (n0 < 196) {
        qA0 = *reinterpret_cast<const s8v*>(&Qh[(size_t)n0 * 16 + (g & 1) * 8]);
        if (g < 2) qB0 = *reinterpret_cast<const s8v*>(&Ql[(size_t)n0 * 16 + g * 8]);
    }
    if (two) {
        qA1 = *reinterpret_cast<const s8v*>(&Qh[(size_t)n1 * 16 + (g & 1) * 8]);
        if (g < 2) qB1 = *reinterpret_cast<const s8v*>(&Ql[(size_t)n1 * 16 + g * 8]);
    }

    f4v O00 = (f4v)0.0f, O01 = (f4v)0.0f;   // tile0 d-halves
    f4v O10 = (f4v)0.0f, O11 = (f4v)0.0f;   // tile1 d-halves
    float M0 = -1e30f, L0 = 0.0f, M1 = -1e30f, L1 = 0.0f;

#pragma unroll 1
    for (int ch = 0; ch < 13; ++ch) {
        int m0 = ch * 64;
        int subLim = (ch == 12) ? 1 : 4;
        int mlim = (ch == 12) ? 16 : 64;

        float s0[4][4], s1[4][4];
#pragma unroll
        for (int sub = 0; sub < 4; ++sub) {
            if (sub < subLim) {
                int mg = m0 + sub * 16 + fr;
                s8v af = *reinterpret_cast<const s8v*>(&Kbase[(size_t)mg * 16 + (g & 1) * 8]);
                f4v a0 = (f4v)0.0f;
                a0 = __builtin_amdgcn_mfma_f32_16x16x32_bf16(af, qA0, a0, 0, 0, 0);
                a0 = __builtin_amdgcn_mfma_f32_16x16x32_bf16(af, qB0, a0, 0, 0, 0);
                s4v bv0 = *reinterpret_cast<const s4v*>(&bB0[m0 + sub * 16 + g * 4]);
#pragma unroll
                for (int e = 0; e < 4; ++e)
                    s0[sub][e] = a0[e] * SCALE_ATTN2 + bf16_to_f((unsigned short)bv0[e]);
                if (two) {
                    f4v a1 = (f4v)0.0f;
                    a1 = __builtin_amdgcn_mfma_f32_16x16x32_bf16(af, qA1, a1, 0, 0, 0);
                    a1 = __builtin_amdgcn_mfma_f32_16x16x32_bf16(af, qB1, a1, 0, 0, 0);
                    s4v bv1 = *reinterpret_cast<const s4v*>(&bB1[m0 + sub * 16 + g * 4]);
#pragma unroll
                    for (int e = 0; e < 4; ++e)
                        s1[sub][e] = a1[e] * SCALE_ATTN2 + bf16_to_f((unsigned short)bv1[e]);
                } else {
#pragma unroll
                    for (int e = 0; e < 4; ++e) s1[sub][e] = -1e30f;
                }
            } else {
#pragma unroll
                for (int e = 0; e < 4; ++e) { s0[sub][e] = -1e30f; s1[sub][e] = -1e30f; }
            }
        }

        // ---- softmax tile0 ----
        {
            float mx = s0[0][0];
#pragma unroll
            for (int sub = 0; sub < 4; ++sub)
#pragma unroll
                for (int e = 0; e < 4; ++e) mx = fmaxf(mx, s0[sub][e]);
            mx = fmaxf(mx, __shfl_xor(mx, 16));
            mx = fmaxf(mx, __shfl_xor(mx, 32));
            if (__any(mx > M0 + 8.0f)) {
                float Mn = fmaxf(M0, mx);
                float corr = exp2f(M0 - Mn);
                L0 *= corr;
#pragma unroll
                for (int e = 0; e < 4; ++e) { O00[e] *= corr; O01[e] *= corr; }
                M0 = Mn;
            }
            float Ls = 0.0f;
#pragma unroll
            for (int sub = 0; sub < 4; ++sub) {
                float p[4];
#pragma unroll
                for (int e = 0; e < 4; ++e) {
                    int mml = sub * 16 + g * 4 + e;
                    float pv = exp2f(s0[sub][e] - M0);
                    p[e] = (mml < mlim) ? pv : 0.0f;
                    Ls += p[e];
                }
                unsigned w0, w1;
                asm("v_cvt_pk_bf16_f32 %0, %1, %2" : "=v"(w0) : "v"(p[0]), "v"(p[1]));
                asm("v_cvt_pk_bf16_f32 %0, %1, %2" : "=v"(w1) : "v"(p[2]), "v"(p[3]));
                int mb = sub * 16 + g * 4;
                *reinterpret_cast<unsigned*>(&Pl[w][0][fr][mb]) = w0;
                *reinterpret_cast<unsigned*>(&Pl[w][0][fr][mb + 2]) = w1;
            }
            Ls += __shfl_xor(Ls, 16);
            Ls += __shfl_xor(Ls, 32);
            L0 += Ls;
        }
        // ---- softmax tile1 ----
        if (two) {
            float mx = s1[0][0];
#pragma unroll
            for (int sub = 0; sub < 4; ++sub)
#pragma unroll
                for (int e = 0; e < 4; ++e) mx = fmaxf(mx, s1[sub][e]);
            mx = fmaxf(mx, __shfl_xor(mx, 16));
            mx = fmaxf(mx, __shfl_xor(mx, 32));
            if (__any(mx > M1 + 8.0f)) {
                float Mn = fmaxf(M1, mx);
                float corr = exp2f(M1 - Mn);
                L1 *= corr;
#pragma unroll
                for (int e = 0; e < 4; ++e) { O10[e] *= corr; O11[e] *= corr; }
                M1 = Mn;
            }
            float Ls = 0.0f;
#pragma unroll
            for (int sub = 0; sub < 4; ++sub) {
                float p[4];
#pragma unroll
                for (int e = 0; e < 4; ++e) {
                    int mml = sub * 16 + g * 4 + e;
                    float pv = exp2f(s1[sub][e] - M1);
                    p[e] = (mml < mlim) ? pv : 0.0f;
                    Ls += p[e];
                }
                unsigned w0, w1;
                asm("v_cvt_pk_bf16_f32 %0, %1, %2" : "=v"(w0) : "v"(p[0]), "v"(p[1]));
                asm("v_cvt_pk_bf16_f32 %0, %1, %2" : "=v"(w1) : "v"(p[2]), "v"(p[3]));
                int mb = sub * 16 + g * 4;
                *reinterpret_cast<unsigned*>(&Pl[w][1][fr][mb]) = w0;
                *reinterpret_cast<unsigned*>(&Pl[w][1][fr][mb + 2]) = w1;
            }
            Ls += __shfl_xor(Ls, 16);
            Ls += __shfl_xor(Ls, 32);
            L1 += Ls;
        }

        // ---- PV: V fragments shared by both tiles ----
#pragma unroll
        for (int kc = 0; kc < 2; ++kc) {
            int mf0 = m0 + kc * 32 + g * 8;
            s8v v0 = (s8v)0, v1 = (s8v)0;
            if (mf0 + 8 <= 784) {
                v0 = *reinterpret_cast<const s8v*>(&Vb[(size_t)fr * 784 + mf0]);
                v1 = *reinterpret_cast<const s8v*>(&Vb[(size_t)(16 + fr) * 784 + mf0]);
            }
            s8v pf0 = *reinterpret_cast<const s8v*>(&Pl[w][0][fr][kc * 32 + g * 8]);
            O00 = __builtin_amdgcn_mfma_f32_16x16x32_bf16(v0, pf0, O00, 0, 0, 0);
            O01 = __builtin_amdgcn_mfma_f32_16x16x32_bf16(v1, pf0, O01, 0, 0, 0);
            if (two) {
                s8v pf1 = *reinterpret_cast<const s8v*>(&Pl[w][1][fr][kc * 32 + g * 8]);
                O10 = __builtin_amdgcn_mfma_f32_16x16x32_bf16(v0, pf1, O10, 0, 0, 0);
                O11 = __builtin_amdgcn_mfma_f32_16x16x32_bf16(v1, pf1, O11, 0, 0, 0);
            }
        }
    }

    // ---- epilogue -> actT swizzled hi/lo tiles ----
    if (n0 < 196) {
        float inv = 1.0f / L0;
        int r = n0 & 63, ntl = n0 >> 6;
        int sw = (r & 7) << 3;
#pragma unroll
        for (int dt = 0; dt < 2; ++dt) {
            int c0 = h * 32 + dt * 16 + g * 4;
            f4v Ov = dt ? O01 : O00;
            s4v hv, lv;
#pragma unroll
            for (int e = 0; e < 4; ++e) {
                float z = hswish(Ov[e] * inv);
                unsigned short hh = bf16_rn(z);
                hv[e] = (short)hh; lv[e] = (short)bf16_rn(z - bf16_to_f(hh));
            }
            int ct = c0 >> 6, c2 = c0 & 63;
            size_t tb = ((((size_t)b * 4 + ntl) * 4 + ct) << 13);  // shorts
            int idx2 = r * 64 + (c2 ^ sw);
            *reinterpret_cast<s4v*>(&actT[tb + idx2]) = hv;
            *reinterpret_cast<s4v*>(&actT[tb + 4096 + idx2]) = lv;
        }
    }
    if (two) {
        float inv = 1.0f / L1;
        int r = n1 & 63, ntl = n1 >> 6;
        int sw = (r & 7) << 3;
#pragma unroll
        for (int dt = 0; dt < 2; ++dt) {
            int c0 = h * 32 + dt * 16 + g * 4;
            f4v Ov = dt ? O11 : O10;
            s4v hv, lv;
#pragma unroll
            for (int e = 0; e < 4; ++e) {
                float z = hswish(Ov[e] * inv);
                unsigned short hh = bf16_rn(z);
                hv[e] = (short)hh; lv[e] = (short)bf16_rn(z - bf16_to_f(hh));
            }
            int ct = c0 >> 6, c2 = c0 & 63;
            size_t tb = ((((size_t)b * 4 + ntl) * 4 + ct) << 13);  // shorts
            int idx2 = r * 64 + (c2 ^ sw);
            *reinterpret_cast<s4v*>(&actT[tb + idx2]) = hv;
            *reinterpret_cast<s4v*>(&actT[tb + 4096 + idx2]) = lv;
        }
    }
}

// ---------------- proj GEMM: 128o x 64n from actT tiles -> fp32 out --------
__global__ __launch_bounds__(256)
void gemm_proj(const short* __restrict__ actT,
               const short* __restrict__ Whi, const short* __restrict__ Wlo,
               const float* __restrict__ G, const float* __restrict__ Bb,
               const float* __restrict__ Mm, const float* __restrict__ Vv,
               float* __restrict__ out)
{
    __shared__ short Bt[2][64][64];
    __shared__ float scs[128], shs[128];

    int nt = blockIdx.x, oy = blockIdx.y, b = blockIdx.z;
    int oBase = oy * 128;
    int tid = threadIdx.x, w = tid >> 6, l = tid & 63;
    int fr = l & 15, g = l >> 4;

    if (tid < 128) {
        int o = oBase + tid;
        float sc = G[o] * rsqrtf(Vv[o] + BN_EPS);
        scs[tid] = sc; shs[tid] = Bb[o] - Mm[o] * sc;
    }

    f4v acc[2][4];
#pragma unroll
    for (int i = 0; i < 2; ++i)
#pragma unroll
        for (int j = 0; j < 4; ++j) acc[i][j] = (f4v)0.0f;

    const char* tilesrc = (const char*)(actT) + ((((size_t)b * 4 + nt) * 4) << 14);
    char* ldsbase = (char*)&Bt[0][0][0];

    for (int ct = 0; ct < 4; ++ct) {
        __syncthreads();
        {
            const char* src = tilesrc + ((size_t)ct << 14) + w * 4096 + l * 16;
            char* dst = ldsbase + w * 4096;
#pragma unroll
            for (int j = 0; j < 4; ++j)
                gload_lds16(src + j * 1024, dst + j * 1024);
        }
        __syncthreads();
#pragma unroll
        for (int ks = 0; ks < 2; ++ks) {
            s8v ah[2], al[2];
#pragma unroll
            for (int mf = 0; mf < 2; ++mf) {
                int o = oBase + w * 32 + mf * 16 + fr;
                size_t wi = (size_t)o * 256 + ct * 64 + ks * 32 + g * 8;
                ah[mf] = *reinterpret_cast<const s8v*>(&Whi[wi]);
                al[mf] = *reinterpret_cast<const s8v*>(&Wlo[wi]);
            }
#pragma unroll
            for (int nf = 0; nf < 4; ++nf) {
                int r = nf * 16 + fr;
                int ci = (ks * 32 + g * 8) ^ ((r & 7) << 3);
                s8v bh = *reinterpret_cast<const s8v*>(&Bt[0][r][ci]);
                s8v bl = *reinterpret_cast<const s8v*>(&Bt[1][r][ci]);
#pragma unroll
                for (int mf = 0; mf < 2; ++mf) {
                    acc[mf][nf] = __builtin_amdgcn_mfma_f32_16x16x32_bf16(ah[mf], bh, acc[mf][nf], 0, 0, 0);
                    acc[mf][nf] = __builtin_amdgcn_mfma_f32_16x16x32_bf16(ah[mf], bl, acc[mf][nf], 0, 0, 0);
                    acc[mf][nf] = __builtin_amdgcn_mfma_f32_16x16x32_bf16(al[mf], bh, acc[mf][nf], 0, 0, 0);
                }
            }
        }
    }

#pragma unroll
    for (int mf = 0; mf < 2; ++mf) {
        int ol = w * 32 + mf * 16 + g * 4;
#pragma unroll
        for (int nf = 0; nf < 4; ++nf) {
            int n = nt * 64 + nf * 16 + fr;
            if (n < 196) {
#pragma unroll
                for (int e = 0; e < 4; ++e) {
                    float z = hswish(acc[mf][nf][e] * scs[ol + e] + shs[ol + e]);
                    out[((size_t)b * 512 + oBase + ol + e) * 196 + n] = z;
                }
            }
        }
    }
}

// ---------------------------------------------------------------------------
extern "C" void kernel_launch(void* const* d_in, const int* in_sizes, int n_in,
                              void* d_out, int out_size, void* d_ws, size_t ws_size,
                              hipStream_t stream) {
    const float* x      = (const float*)d_in[0];
    const float* kv_w   = (const float*)d_in[1];
    const float* kv_g   = (const float*)d_in[2];
    const float* kv_b   = (const float*)d_in[3];
    const float* kv_m   = (const float*)d_in[4];
    const float* kv_v   = (const float*)d_in[5];
    const float* q_w    = (const float*)d_in[6];
    const float* q_g    = (const float*)d_in[7];
    const float* q_b    = (const float*)d_in[8];
    const float* q_m    = (const float*)d_in[9];
    const float* q_v    = (const float*)d_in[10];
    const float* proj_w = (const float*)d_in[11];
    const float* proj_g = (const float*)d_in[12];
    const float* proj_b = (const float*)d_in[13];
    const float* proj_m = (const float*)d_in[14];
    const float* proj_v = (const float*)d_in[15];
    const float* ab     = (const float*)d_in[16];
    const int*   idxs   = (const int*)d_in[17];
    float* out = (float*)d_out;

    int n_off = in_sizes[16] / 8;

    // ---- workspace layout (bytes, 256-aligned) ----
    char* p = (char*)d_ws;
    size_t off = 0;
    auto alloc = [&](size_t bytes) -> char* {
        char* r = p + off;
        off += (bytes + 255) & ~(size_t)255;
        return r;
    };
    short* Kthi = (short*)alloc((size_t)64 * 8 * 784 * 16 * 2);
    short* Ktlo = (short*)alloc((size_t)64 * 8 * 784 * 16 * 2);
    short* Vbf  = (short*)alloc((size_t)64 * 8 * 32 * 784 * 2);
    short* Qthi = (short*)alloc((size_t)64 * 8 * 196 * 16 * 2);
    short* Qtlo = (short*)alloc((size_t)64 * 8 * 196 * 16 * 2);
    unsigned short* biasF = (unsigned short*)alloc((size_t)8 * 208 * 784 * 2);
    short* Wkvh = (short*)alloc((size_t)384 * 256 * 2);
    short* Wkvl = (short*)alloc((size_t)384 * 256 * 2);
    short* Wqh  = (short*)alloc((size_t)128 * 256 * 2);
    short* Wql  = (short*)alloc((size_t)128 * 256 * 2);
    short* Wpjh = (short*)alloc((size_t)512 * 256 * 2);
    short* Wpjl = (short*)alloc((size_t)512 * 256 * 2);
    short* xT   = (short*)alloc((size_t)64 * 13 * 4 * 16384);
    short* actT = xT;   // alias: xT consumed by gemm_kv before attn writes actT

    // 1. W pre-converts
    wprep<<<dim3(64), 256, 0, stream>>>(kv_w, Wkvh, Wkvl, 384 * 256 / 4);
    wprep<<<dim3(64), 256, 0, stream>>>(q_w, Wqh, Wql, 128 * 256 / 4);
    wprep<<<dim3(64), 256, 0, stream>>>(proj_w, Wpjh, Wpjl, 512 * 256 / 4);
    // 2. x transpose/convert/swizzle tiles
    xprep<<<dim3(13, 64), 256, 0, stream>>>(x, xT);
    // 3. bias gather (bf16, [h][208][784], pre-scaled by log2e, tail zeroed)
    bias_kernel<<<dim3((208 * 784 + 255) / 256), 256, 0, stream>>>(ab, idxs, biasF, n_off);
    // 4. kv GEMM -> Kt hi/lo + Vbf
    gemm_kv<<<dim3(13, 3, 64), 256, 0, stream>>>(xT, Wkvh, Wkvl, kv_g, kv_b, kv_m, kv_v,
                                                 Kthi, Ktlo, Vbf);
    // 5. q GEMM -> Qt hi/lo
    gemm_q<<<dim3(4, 1, 64), 256, 0, stream>>>(x, Wqh, Wql, q_g, q_b, q_m, q_v,
                                               Qthi, Qtlo);
    // 6. attention: 7 waves per (b,h), 2 tiles/wave -> actT tiles
    attn_mfma<<<dim3(896), 256, 0, stream>>>(Kthi, Ktlo, Vbf, Qthi, Qtlo, biasF, actT);
    // 7. proj GEMM -> out
    gemm_proj<<<dim3(4, 4, 64), 256, 0, stream>>>(actT, Wpjh, Wpjl,
                                                  proj_g, proj_b, proj_m, proj_v, out);
}